// Round 1
// baseline (288.217 us; speedup 1.0000x reference)
//
#include <hip/hip_runtime.h>

// WaveCell: y = denom * (2/dt^2 * y1 - (1/dt^2 - b/dt) * y2 + c^2 * lap(y1))
// denom = 1 / (1/dt^2 + b/dt); lap = 5-point stencil with zero padding, / h^2.
// Outputs: (y, y1) concatenated flat in d_out.

#define WAVE_DT 0.001f
#define WAVE_H  10.0f

__global__ __launch_bounds__(256) void WaveCell_790273982844_kernel(
    const float* __restrict__ c,
    const float* __restrict__ b,
    const float* __restrict__ y1,
    const float* __restrict__ y2,
    float* __restrict__ out_y,
    float* __restrict__ out_y1)
{
    constexpr int W  = 4096;
    constexpr int H  = 4096;
    constexpr int W4 = W / 4;          // 1024 float4 per row

    const float inv_dt2 = 1.0f / (WAVE_DT * WAVE_DT);  // 1e6
    const float inv_dt  = 1.0f / WAVE_DT;              // 1e3
    const float inv_h2  = 1.0f / (WAVE_H * WAVE_H);    // 0.01

    const long t = (long)blockIdx.x * blockDim.x + threadIdx.x;  // float4 index
    const int  j4      = (int)(t & (W4 - 1));          // column group
    const long rowIdx  = t >> 10;                      // b*H + i
    const int  i       = (int)(rowIdx & (H - 1));      // row within image
    const int  j       = j4 << 2;                      // starting column

    const float* rowC = c  + (long)i * W;
    const float* rowB = b  + (long)i * W;
    const float* row1 = y1 + rowIdx * W;
    const float* row2 = y2 + rowIdx * W;

    const float4 ctr = *(const float4*)(row1 + j);
    const float4 up  = (i > 0)     ? *(const float4*)(row1 - W + j) : make_float4(0.f, 0.f, 0.f, 0.f);
    const float4 dn  = (i < H - 1) ? *(const float4*)(row1 + W + j) : make_float4(0.f, 0.f, 0.f, 0.f);
    const float  lf  = (j > 0)     ? row1[j - 1] : 0.0f;
    const float  rt  = (j + 4 < W) ? row1[j + 4] : 0.0f;
    const float4 cc  = *(const float4*)(rowC + j);
    const float4 bb  = *(const float4*)(rowB + j);
    const float4 p2  = *(const float4*)(row2 + j);

    const float ce[4]  = {ctr.x, ctr.y, ctr.z, ctr.w};
    const float ue[4]  = {up.x,  up.y,  up.z,  up.w};
    const float de[4]  = {dn.x,  dn.y,  dn.z,  dn.w};
    const float le[4]  = {lf,    ctr.x, ctr.y, ctr.z};
    const float re[4]  = {ctr.y, ctr.z, ctr.w, rt};
    const float cv[4]  = {cc.x,  cc.y,  cc.z,  cc.w};
    const float bv[4]  = {bb.x,  bb.y,  bb.z,  bb.w};
    const float y2e[4] = {p2.x,  p2.y,  p2.z,  p2.w};

    float yo[4];
#pragma unroll
    for (int k = 0; k < 4; ++k) {
        const float lap   = (ue[k] + de[k] + le[k] + re[k] - 4.0f * ce[k]) * inv_h2;
        const float bdt   = bv[k] * inv_dt;
        const float denom = 1.0f / (inv_dt2 + bdt);
        yo[k] = denom * (2.0f * inv_dt2 * ce[k]
                         - (inv_dt2 - bdt) * y2e[k]
                         + cv[k] * cv[k] * lap);
    }

    float* o1 = out_y  + rowIdx * W + j;
    float* o2 = out_y1 + rowIdx * W + j;
    *(float4*)o1 = make_float4(yo[0], yo[1], yo[2], yo[3]);
    *(float4*)o2 = ctr;
}

extern "C" void kernel_launch(void* const* d_in, const int* in_sizes, int n_in,
                              void* d_out, int out_size, void* d_ws, size_t ws_size,
                              hipStream_t stream) {
    (void)in_sizes; (void)n_in; (void)d_ws; (void)ws_size; (void)out_size;

    const float* c  = (const float*)d_in[0];
    const float* b  = (const float*)d_in[1];
    const float* y1 = (const float*)d_in[2];
    const float* y2 = (const float*)d_in[3];

    const long B = 4, H = 4096, W = 4096;
    const long N = B * H * W;                 // 67,108,864 elements per field

    float* out_y  = (float*)d_out;
    float* out_y1 = out_y + N;

    const long totalThreads = N / 4;          // one float4 per thread
    const int  block = 256;
    const long grid  = totalThreads / block;  // 65536

    WaveCell_790273982844_kernel<<<(unsigned)grid, block, 0, stream>>>(
        c, b, y1, y2, out_y, out_y1);
}

// Round 3
// 246.765 us; speedup vs baseline: 1.1680x; 1.1680x over previous
//
#include <hip/hip_runtime.h>

// WaveCell: y = denom * (2/dt^2 * y1 - (1/dt^2 - b/dt) * y2 + c^2 * lap(y1))
// denom = 1 / (1/dt^2 + b/dt); lap = 5-point stencil with zero padding, / h^2.
// Outputs: (y, y1) concatenated flat in d_out.
//
// R3: (a) XCD-contiguous bijective block swizzle — row i and row i±1 blocks
//     land on the SAME XCD so up/down stencil reads hit local L2 instead of
//     taking the cross-XCD L3 path; (b) nontemporal stores (outputs are
//     never re-read) to keep L2 for y1 row reuse. Native vec4 type for the
//     nontemporal builtin (HIP float4 is a class -> rejected by clang).

#define WAVE_DT 0.001f
#define WAVE_H  10.0f

typedef float fvec4 __attribute__((ext_vector_type(4)));

__global__ __launch_bounds__(256) void WaveCell_790273982844_kernel(
    const float* __restrict__ c,
    const float* __restrict__ b,
    const float* __restrict__ y1,
    const float* __restrict__ y2,
    float* __restrict__ out_y,
    float* __restrict__ out_y1)
{
    constexpr int W  = 4096;
    constexpr int H  = 4096;
    constexpr int W4 = W / 4;          // 1024 float4 per row

    const float inv_dt2 = 1.0f / (WAVE_DT * WAVE_DT);  // 1e6
    const float inv_dt  = 1.0f / WAVE_DT;              // 1e3
    const float inv_h2  = 1.0f / (WAVE_H * WAVE_H);    // 0.01

    // XCD-contiguous swizzle: hw slot n -> XCD n%8; logical block
    // (n%8)*cpx + n/8 gives XCD k the contiguous band [k*cpx, (k+1)*cpx).
    // nwg = 65536, divisible by 8 -> bijective.
    const unsigned nwg = gridDim.x;
    const unsigned cpx = nwg >> 3;
    const unsigned bid = blockIdx.x;
    const unsigned swz = (bid & 7u) * cpx + (bid >> 3);

    const long t = (long)swz * blockDim.x + threadIdx.x;  // float4 index
    const int  j4      = (int)(t & (W4 - 1));          // column group
    const long rowIdx  = t >> 10;                      // b*H + i
    const int  i       = (int)(rowIdx & (H - 1));      // row within image
    const int  j       = j4 << 2;                      // starting column

    const float* rowC = c  + (long)i * W;
    const float* rowB = b  + (long)i * W;
    const float* row1 = y1 + rowIdx * W;
    const float* row2 = y2 + rowIdx * W;

    const fvec4 zero = (fvec4)0.0f;
    const fvec4 ctr = *(const fvec4*)(row1 + j);
    const fvec4 up  = (i > 0)     ? *(const fvec4*)(row1 - W + j) : zero;
    const fvec4 dn  = (i < H - 1) ? *(const fvec4*)(row1 + W + j) : zero;
    const float lf  = (j > 0)     ? row1[j - 1] : 0.0f;
    const float rt  = (j + 4 < W) ? row1[j + 4] : 0.0f;
    const fvec4 cc  = *(const fvec4*)(rowC + j);
    const fvec4 bb  = *(const fvec4*)(rowB + j);
    const fvec4 p2  = *(const fvec4*)(row2 + j);

    const float le[4] = {lf, ctr.x, ctr.y, ctr.z};
    const float re[4] = {ctr.y, ctr.z, ctr.w, rt};

    fvec4 yo;
#pragma unroll
    for (int k = 0; k < 4; ++k) {
        const float lap   = (up[k] + dn[k] + le[k] + re[k] - 4.0f * ctr[k]) * inv_h2;
        const float bdt   = bb[k] * inv_dt;
        const float denom = 1.0f / (inv_dt2 + bdt);
        yo[k] = denom * (2.0f * inv_dt2 * ctr[k]
                         - (inv_dt2 - bdt) * p2[k]
                         + cc[k] * cc[k] * lap);
    }

    float* o1 = out_y  + rowIdx * W + j;
    float* o2 = out_y1 + rowIdx * W + j;
    __builtin_nontemporal_store(yo,  (fvec4*)o1);
    __builtin_nontemporal_store(ctr, (fvec4*)o2);
}

extern "C" void kernel_launch(void* const* d_in, const int* in_sizes, int n_in,
                              void* d_out, int out_size, void* d_ws, size_t ws_size,
                              hipStream_t stream) {
    (void)in_sizes; (void)n_in; (void)d_ws; (void)ws_size; (void)out_size;

    const float* c  = (const float*)d_in[0];
    const float* b  = (const float*)d_in[1];
    const float* y1 = (const float*)d_in[2];
    const float* y2 = (const float*)d_in[3];

    const long B = 4, H = 4096, W = 4096;
    const long N = B * H * W;                 // 67,108,864 elements per field

    float* out_y  = (float*)d_out;
    float* out_y1 = out_y + N;

    const long totalThreads = N / 4;          // one float4 per thread
    const int  block = 256;
    const long grid  = totalThreads / block;  // 65536

    WaveCell_790273982844_kernel<<<(unsigned)grid, block, 0, stream>>>(
        c, b, y1, y2, out_y, out_y1);
}